// Round 1
// baseline (241.353 us; speedup 1.0000x reference)
//
#include <hip/hip_runtime.h>
#include <hip/hip_bf16.h>
#include <stdint.h>

#define BDIM 32
#define SDIM 4096
#define SP1  4097
#define EDIM 256
#define FDIM 256
#define LDIM 50

typedef __attribute__((ext_vector_type(8))) short bf16x8v;
typedef __attribute__((ext_vector_type(4))) float f32x4;

__device__ __forceinline__ unsigned short f2bf(float f) {
    union { float f; uint32_t u; } v; v.f = f;
    uint32_t u = v.u;
    uint32_t r = (u + 0x7fffu + ((u >> 16) & 1u)) >> 16;
    return (unsigned short)r;
}

__device__ __forceinline__ float fast_tanh(float x) {
    float e = __expf(2.0f * x);
    return (e - 1.0f) / (e + 1.0f);
}

// ---- Prep 1: conv_w (f,e,k) fp32 -> Wb[f][kk] bf16, kk = k*256+e ----
__global__ void prep_wb(const float* __restrict__ conv_w, unsigned short* __restrict__ Wb) {
    int o = blockIdx.x * 256 + threadIdx.x;      // 256*1024 elems
    int e = o & 255, k = (o >> 8) & 3, f = o >> 10;
    Wb[o] = f2bf(conv_w[f * 1024 + e * 4 + k]);
}

// ---- Prep 2: W2k[k/8][c][k%8] bf16; c<64: U_w col, c>=64: final_w col ----
__global__ void prep_w2(const float* __restrict__ U_w, const float* __restrict__ final_w,
                        unsigned short* __restrict__ W2k) {
    int o = blockIdx.x * 256 + threadIdx.x;      // 32*128*8 = 32768
    int j = o & 7, c = (o >> 3) & 127, g = o >> 10;
    int k = g * 8 + j;
    int l = c & 63;
    float v = 0.f;
    if (l < LDIM) v = (c < 64) ? U_w[l * FDIM + k] : final_w[l * FDIM + k];
    W2k[o] = f2bf(v);
}

// ---- K1: fused embedding + conv1d + tanh -> H (bf16, [b][t][f]) ----
// Block: 128 output positions x 256 filters. MFMA: A = weights (M=f), B = patches (N=t).
__global__ __launch_bounds__(256, 2) void conv_kernel(
    const int* __restrict__ ids, const float* __restrict__ emb,
    const unsigned short* __restrict__ Wb, const float* __restrict__ conv_b,
    unsigned short* __restrict__ H)
{
    __shared__ uint32_t xs[131 * 128];  // 131 rows x 512B (bf16[256]/row), XOR-swizzled

    const int tid  = threadIdx.x;
    const int lane = tid & 63;
    const int wid  = tid >> 6;
    const int b    = blockIdx.y;
    const int t0   = blockIdx.x * 128;

    // Stage x-tile: rows r=0..130 correspond to input position p = t0-2+r (zero-padded).
    for (int r = wid; r < 131; r += 4) {
        int p = t0 - 2 + r;
        uint32_t lo = 0, hi = 0;
        if (p >= 0 && p < SDIM) {
            int id = ids[b * SDIM + p];
            float4 v = *(const float4*)(emb + (size_t)id * EDIM + lane * 4);
            lo = (uint32_t)f2bf(v.x) | ((uint32_t)f2bf(v.y) << 16);
            hi = (uint32_t)f2bf(v.z) | ((uint32_t)f2bf(v.w) << 16);
        }
        int ob  = (lane * 8) ^ ((r & 7) << 4);   // swizzled byte offset within row
        int idx = (r * 512 + ob) >> 2;
        xs[idx] = lo; xs[idx + 1] = hi;
    }
    __syncthreads();

    const int fbase = (wid & 1) * 128;   // wave covers 128 filters (M)
    const int tbase = (wid >> 1) * 64;   // wave covers 64 t-positions (N)
    const int l15   = lane & 15;
    const int kg    = (lane >> 4) * 8;

    f32x4 acc[8][4];
    #pragma unroll
    for (int a = 0; a < 8; ++a)
        #pragma unroll
        for (int n = 0; n < 4; ++n) acc[a][n] = (f32x4){0.f, 0.f, 0.f, 0.f};

    for (int kk0 = 0; kk0 < 1024; kk0 += 32) {
        const int k  = kk0 >> 8;     // conv tap
        const int e0 = kk0 & 255;    // embed-channel base
        bf16x8v af[8], bfr[4];
        #pragma unroll
        for (int a = 0; a < 8; ++a) {
            // A[f][kk]: lane row f = fbase + a*16 + (lane&15), k-chunk kg..kg+7
            af[a] = *(const bf16x8v*)(Wb + (size_t)(fbase + a * 16 + l15) * 1024 + kk0 + kg);
        }
        #pragma unroll
        for (int n = 0; n < 4; ++n) {
            // B[kk][t]: lane col t = tbase + n*16 + (lane&15); e = e0+kg..+7 at xs row r = t + k
            int r  = tbase + n * 16 + l15 + k;
            int ob = (e0 * 2 + (lane >> 4) * 16) ^ ((r & 7) << 4);
            bfr[n] = *(const bf16x8v*)&xs[(r * 512 + ob) >> 2];
        }
        #pragma unroll
        for (int a = 0; a < 8; ++a)
            #pragma unroll
            for (int n = 0; n < 4; ++n)
                acc[a][n] = __builtin_amdgcn_mfma_f32_16x16x32_bf16(af[a], bfr[n], acc[a][n], 0, 0, 0);
    }

    // Epilogue: D[r=f][c=t]; lane holds 4 consecutive f at one t -> packed 8B store.
    #pragma unroll
    for (int n = 0; n < 4; ++n) {
        int t = t0 + tbase + n * 16 + l15;
        if (t > SDIM) continue;
        #pragma unroll
        for (int a = 0; a < 8; ++a) {
            int f0 = fbase + a * 16 + (lane >> 4) * 4;
            float4 cb = *(const float4*)(conv_b + f0);
            f32x4 d = acc[a][n];
            uint2 pk;
            pk.x = (uint32_t)f2bf(fast_tanh(d[0] + cb.x)) | ((uint32_t)f2bf(fast_tanh(d[1] + cb.y)) << 16);
            pk.y = (uint32_t)f2bf(fast_tanh(d[2] + cb.z)) | ((uint32_t)f2bf(fast_tanh(d[3] + cb.w)) << 16);
            *(uint2*)(H + ((size_t)(b * SP1 + t)) * FDIM + f0) = pk;
        }
    }
}

// ---- K2: P = H @ W2 (scores | t), fused chunk-local online-softmax partials ----
__global__ __launch_bounds__(256, 2) void attn_kernel(
    const unsigned short* __restrict__ H, const unsigned short* __restrict__ W2k,
    float* __restrict__ part)
{
    const int tid   = threadIdx.x;
    const int lane  = tid & 63;
    const int ws    = tid >> 6;
    const int b     = blockIdx.y;
    const int chunk = blockIdx.x;
    const int sbase = chunk * 256 + ws * 64;   // wave covers 64 s-rows x 128 cols
    const int l15   = lane & 15;
    const int kg    = (lane >> 4) * 8;

    f32x4 acc[4][8];
    #pragma unroll
    for (int m = 0; m < 4; ++m)
        #pragma unroll
        for (int n = 0; n < 8; ++n) acc[m][n] = (f32x4){0.f, 0.f, 0.f, 0.f};

    for (int step = 0; step < 8; ++step) {
        int k0 = step * 32;
        bf16x8v af[4], bfr[8];
        #pragma unroll
        for (int m = 0; m < 4; ++m) {
            int s  = sbase + m * 16 + l15;
            int sc = s > SDIM ? SDIM : s;       // clamp; masked in reduction
            af[m] = *(const bf16x8v*)(H + ((size_t)(b * SP1 + sc)) * FDIM + k0 + kg);
        }
        #pragma unroll
        for (int n = 0; n < 8; ++n) {
            int g = (k0 >> 3) + (lane >> 4);
            bfr[n] = *(const bf16x8v*)(W2k + ((size_t)(g * 128 + n * 16 + l15)) * 8);
        }
        #pragma unroll
        for (int m = 0; m < 4; ++m)
            #pragma unroll
            for (int n = 0; n < 8; ++n)
                acc[m][n] = __builtin_amdgcn_mfma_f32_16x16x32_bf16(af[m], bfr[n], acc[m][n], 0, 0, 0);
    }

    // Lane-local softmax partials: col c(=label l) score in acc[.][nf], t in acc[.][nf+4] (same lane).
    __shared__ float redm[4][64], redse[4][64], redst[4][64];
    #pragma unroll
    for (int nf = 0; nf < 4; ++nf) {
        int l = nf * 16 + l15;
        float mx = -1e30f;
        #pragma unroll
        for (int m = 0; m < 4; ++m)
            #pragma unroll
            for (int i = 0; i < 4; ++i) {
                int s = sbase + m * 16 + (lane >> 4) * 4 + i;
                if (s <= SDIM) mx = fmaxf(mx, acc[m][nf][i]);
            }
        float se = 0.f, st = 0.f;
        #pragma unroll
        for (int m = 0; m < 4; ++m)
            #pragma unroll
            for (int i = 0; i < 4; ++i) {
                int s = sbase + m * 16 + (lane >> 4) * 4 + i;
                if (s <= SDIM) {
                    float e = __expf(acc[m][nf][i] - mx);
                    se += e;
                    st += e * acc[m][nf + 4][i];
                }
            }
        #pragma unroll
        for (int d = 16; d <= 32; d <<= 1) {
            float mo  = __shfl_xor(mx, d);
            float seo = __shfl_xor(se, d);
            float sto = __shfl_xor(st, d);
            float M  = fmaxf(mx, mo);
            float w0 = __expf(mx - M), w1 = __expf(mo - M);
            se = se * w0 + seo * w1;
            st = st * w0 + sto * w1;
            mx = M;
        }
        if (lane < 16) { redm[ws][l] = mx; redse[ws][l] = se; redst[ws][l] = st; }
    }
    __syncthreads();
    if (tid < 64) {
        float mx = redm[0][tid], se = redse[0][tid], st = redst[0][tid];
        #pragma unroll
        for (int w = 1; w < 4; ++w) {
            float mo = redm[w][tid], seo = redse[w][tid], sto = redst[w][tid];
            float M  = fmaxf(mx, mo);
            float w0 = __expf(mx - M), w1 = __expf(mo - M);
            se = se * w0 + seo * w1;
            st = st * w0 + sto * w1;
            mx = M;
        }
        if (tid < LDIM) {
            size_t o = ((size_t)(b * 17 + chunk) * LDIM + tid) * 3;
            part[o] = mx; part[o + 1] = se; part[o + 2] = st;
        }
    }
}

// ---- K3: merge 17 chunk partials -> logits ----
__global__ void final_kernel(const float* __restrict__ part, const float* __restrict__ final_b,
                             float* __restrict__ out)
{
    int b = blockIdx.x, l = threadIdx.x;
    if (l >= LDIM) return;
    float mx = -1e30f, se = 0.f, st = 0.f;
    for (int c = 0; c < 17; ++c) {
        size_t o = ((size_t)(b * 17 + c) * LDIM + l) * 3;
        float mo = part[o], seo = part[o + 1], sto = part[o + 2];
        float M  = fmaxf(mx, mo);
        float w0 = __expf(mx - M), w1 = __expf(mo - M);
        se = se * w0 + seo * w1;
        st = st * w0 + sto * w1;
        mx = M;
    }
    out[b * LDIM + l] = st / se + final_b[l];
}

extern "C" void kernel_launch(void* const* d_in, const int* in_sizes, int n_in,
                              void* d_out, int out_size, void* d_ws, size_t ws_size,
                              hipStream_t stream)
{
    const int*   ids     = (const int*)d_in[0];
    const float* emb     = (const float*)d_in[1];
    const float* conv_w  = (const float*)d_in[2];
    const float* conv_b  = (const float*)d_in[3];
    const float* U_w     = (const float*)d_in[4];
    const float* final_w = (const float*)d_in[5];
    const float* final_b = (const float*)d_in[6];

    char* ws = (char*)d_ws;
    size_t offH  = 0;
    size_t szH   = (size_t)BDIM * SP1 * FDIM * 2;   // 67,125,248 B
    size_t offWb = offH + szH;
    size_t szWb  = 256 * 1024 * 2;                  // 524,288 B
    size_t offW2 = offWb + szWb;
    size_t szW2  = 32768 * 2;                       // 65,536 B
    size_t offP  = offW2 + szW2;                    // partials: 32*17*50*3 fp32

    unsigned short* H   = (unsigned short*)(ws + offH);
    unsigned short* Wb  = (unsigned short*)(ws + offWb);
    unsigned short* W2k = (unsigned short*)(ws + offW2);
    float*          prt = (float*)(ws + offP);

    prep_wb<<<1024, 256, 0, stream>>>(conv_w, Wb);
    prep_w2<<<128, 256, 0, stream>>>(U_w, final_w, W2k);
    conv_kernel<<<dim3(33, 32), 256, 0, stream>>>(ids, emb, Wb, conv_b, H);
    attn_kernel<<<dim3(17, 32), 256, 0, stream>>>(H, W2k, prt);
    final_kernel<<<32, 64, 0, stream>>>(prt, final_b, (float*)d_out);
}

// Round 2
// 149.432 us; speedup vs baseline: 1.6151x; 1.6151x over previous
//
#include <hip/hip_runtime.h>
#include <hip/hip_bf16.h>
#include <stdint.h>

#define BDIM 32
#define SDIM 4096
#define SP1  4097
#define EDIM 256
#define FDIM 256
#define LDIM 50
#define TTILE 96
#define NT    43   // ceil(4097/96)

typedef __attribute__((ext_vector_type(8))) short bf16x8v;
typedef __attribute__((ext_vector_type(4))) float f32x4;

__device__ __forceinline__ unsigned short f2bf(float f) {
    union { float f; uint32_t u; } v; v.f = f;
    uint32_t u = v.u;
    uint32_t r = (u + 0x7fffu + ((u >> 16) & 1u)) >> 16;
    return (unsigned short)r;
}

__device__ __forceinline__ float fast_tanh(float x) {
    float e = __expf(2.0f * x);
    return (e - 1.0f) / (e + 1.0f);
}

__device__ __forceinline__ void load_lds16(const void* g, uint32_t* l) {
    __builtin_amdgcn_global_load_lds(
        (const __attribute__((address_space(1))) uint32_t*)g,
        (__attribute__((address_space(3))) uint32_t*)l, 16, 0, 0);
}

// ---- Prep A: Wb[f][kk] bf16 (kk=k*256+e), W2k[g][c][j] bf16, zero page ----
__global__ void prep_misc(const float* __restrict__ conv_w,
                          const float* __restrict__ U_w, const float* __restrict__ final_w,
                          unsigned short* __restrict__ Wb, unsigned short* __restrict__ W2k,
                          uint32_t* __restrict__ zp) {
    int o = blockIdx.x * 256 + threadIdx.x;          // grid 1024 -> o < 262144
    { int e = o & 255, k = (o >> 8) & 3, f = o >> 10;
      Wb[o] = f2bf(conv_w[f * 1024 + e * 4 + k]); }
    if (o < 32768) {
        int j = o & 7, c = (o >> 3) & 127, g = o >> 10;
        int k = g * 8 + j, l = c & 63;
        float v = 0.f;
        if (l < LDIM) v = (c < 64) ? U_w[l * FDIM + k] : final_w[l * FDIM + k];
        W2k[o] = f2bf(v);
    }
    if (o < 128) zp[o] = 0;
}

// ---- Prep B: embedding table fp32 -> bf16 (row-major unchanged) ----
__global__ void prep_embb(const float* __restrict__ emb, unsigned short* __restrict__ embb) {
    size_t o = ((size_t)blockIdx.x * 256 + threadIdx.x) * 8;
    if (o >= (size_t)30522 * 256) return;
    float4 v0 = *(const float4*)(emb + o);
    float4 v1 = *(const float4*)(emb + o + 4);
    union { unsigned short u[8]; uint4 q; } pk;
    pk.u[0] = f2bf(v0.x); pk.u[1] = f2bf(v0.y); pk.u[2] = f2bf(v0.z); pk.u[3] = f2bf(v0.w);
    pk.u[4] = f2bf(v1.x); pk.u[5] = f2bf(v1.y); pk.u[6] = f2bf(v1.z); pk.u[7] = f2bf(v1.w);
    *(uint4*)(embb + o) = pk.q;
}

// ---- Fused: gather -> conv1d+tanh (LDS H-tile) -> scores|t GEMM -> softmax partials ----
__global__ __launch_bounds__(256, 3) void fused_kernel(
    const int* __restrict__ ids, const unsigned short* __restrict__ embb,
    const unsigned short* __restrict__ Wb, const float* __restrict__ conv_b,
    const unsigned short* __restrict__ W2k, const uint32_t* __restrict__ zp,
    float* __restrict__ part)
{
    __shared__ uint32_t xs[100 * 128];   // 51,200 B: x-tile rows 0..99, then reused as H-tile

    const int tid  = threadIdx.x;
    const int lane = tid & 63;
    const int wid  = tid >> 6;
    const int b    = blockIdx.y;
    const int tile = blockIdx.x;
    const int t0   = tile * TTILE;
    const int l15  = lane & 15;
    const int hi4  = lane >> 4;

    // Stage rows r=0..98 (input pos p = t0-2+r, zero-padded) via global_load_lds,
    // source pre-swizzled so LDS stays linear but layout is XOR-swizzled.
    {
        const int q    = lane & 31;
        const int half = lane >> 5;
        for (int r0 = wid * 2; r0 < 99; r0 += 8) {
            int r = r0 + half;
            int p = t0 - 2 + r;
            const unsigned short* src;
            if (r < 99 && p >= 0 && p < SDIM) {
                int id = ids[b * SDIM + p];
                src = embb + (size_t)id * EDIM + (((q * 16) ^ ((r & 7) << 4)) >> 1);
            } else {
                src = (const unsigned short*)zp + q * 8;
            }
            load_lds16(src, &xs[r0 * 128]);
        }
    }
    __syncthreads();

    // Conv GEMM: each wave 64 filters (M) x 96 positions (N), K=1024.
    const int fbase = wid * 64;
    f32x4 acc[4][6];
    #pragma unroll
    for (int a = 0; a < 4; ++a)
        #pragma unroll
        for (int n = 0; n < 6; ++n) acc[a][n] = (f32x4){0.f, 0.f, 0.f, 0.f};

    for (int kk0 = 0; kk0 < 1024; kk0 += 32) {
        const int k  = kk0 >> 8;
        const int e0 = kk0 & 255;
        bf16x8v af[4], bfr[6];
        #pragma unroll
        for (int a = 0; a < 4; ++a)
            af[a] = *(const bf16x8v*)(Wb + (size_t)(fbase + a * 16 + l15) * 1024 + kk0 + hi4 * 8);
        #pragma unroll
        for (int n = 0; n < 6; ++n) {
            int r  = n * 16 + l15 + k;
            int ob = (e0 * 2 + hi4 * 16) ^ ((r & 7) << 4);
            bfr[n] = *(const bf16x8v*)&xs[(r * 512 + ob) >> 2];
        }
        #pragma unroll
        for (int a = 0; a < 4; ++a)
            #pragma unroll
            for (int n = 0; n < 6; ++n)
                acc[a][n] = __builtin_amdgcn_mfma_f32_16x16x32_bf16(af[a], bfr[n], acc[a][n], 0, 0, 0);
    }
    __syncthreads();   // all waves done reading xs

    // tanh epilogue -> H-tile into LDS (same buffer), XOR-swizzled rows of 512B.
    float4 cb[4];
    #pragma unroll
    for (int a = 0; a < 4; ++a)
        cb[a] = *(const float4*)(conv_b + fbase + a * 16 + hi4 * 4);
    #pragma unroll
    for (int n = 0; n < 6; ++n) {
        int tl = n * 16 + l15;
        #pragma unroll
        for (int a = 0; a < 4; ++a) {
            int f0 = fbase + a * 16 + hi4 * 4;
            f32x4 d = acc[a][n];
            uint2 pk;
            pk.x = (uint32_t)f2bf(fast_tanh(d[0] + cb[a].x)) | ((uint32_t)f2bf(fast_tanh(d[1] + cb[a].y)) << 16);
            pk.y = (uint32_t)f2bf(fast_tanh(d[2] + cb[a].z)) | ((uint32_t)f2bf(fast_tanh(d[3] + cb[a].w)) << 16);
            int byte = tl * 512 + ((f0 * 2) ^ ((tl & 7) << 4));
            *(uint2*)&xs[byte >> 2] = pk;
        }
    }
    __syncthreads();

    // P GEMM: 96 s-rows x 32 cols per wave (cols cbase..+15 = scores, +64 = t), K=256.
    const int cbase = wid * 16;
    f32x4 p[6][2];
    #pragma unroll
    for (int m = 0; m < 6; ++m) { p[m][0] = (f32x4){0,0,0,0}; p[m][1] = (f32x4){0,0,0,0}; }

    for (int step = 0; step < 8; ++step) {
        bf16x8v ha[6], w2[2];
        #pragma unroll
        for (int m = 0; m < 6; ++m) {
            int sl = m * 16 + l15;
            int byte = sl * 512 + ((step * 64 + hi4 * 16) ^ ((sl & 7) << 4));
            ha[m] = *(const bf16x8v*)&xs[byte >> 2];
        }
        #pragma unroll
        for (int n = 0; n < 2; ++n) {
            int c = cbase + n * 64 + l15;
            int g = step * 4 + hi4;
            w2[n] = *(const bf16x8v*)(W2k + (size_t)(g * 128 + c) * 8);
        }
        #pragma unroll
        for (int m = 0; m < 6; ++m) {
            p[m][0] = __builtin_amdgcn_mfma_f32_16x16x32_bf16(ha[m], w2[0], p[m][0], 0, 0, 0);
            p[m][1] = __builtin_amdgcn_mfma_f32_16x16x32_bf16(ha[m], w2[1], p[m][1], 0, 0, 0);
        }
    }

    // Lane-local online-softmax partials: score p[m][0], t p[m][1] (same lane, 4 s-rows/frag).
    float mx = -1e30f;
    #pragma unroll
    for (int m = 0; m < 6; ++m)
        #pragma unroll
        for (int i = 0; i < 4; ++i) {
            int s = t0 + m * 16 + hi4 * 4 + i;
            if (s <= SDIM) mx = fmaxf(mx, p[m][0][i]);
        }
    float se = 0.f, st = 0.f;
    #pragma unroll
    for (int m = 0; m < 6; ++m)
        #pragma unroll
        for (int i = 0; i < 4; ++i) {
            int s = t0 + m * 16 + hi4 * 4 + i;
            if (s <= SDIM) {
                float e = __expf(p[m][0][i] - mx);
                se += e;
                st += e * p[m][1][i];
            }
        }
    #pragma unroll
    for (int d = 16; d <= 32; d <<= 1) {
        float mo  = __shfl_xor(mx, d);
        float seo = __shfl_xor(se, d);
        float sto = __shfl_xor(st, d);
        float M  = fmaxf(mx, mo);
        float w0 = __expf(mx - M), w1 = __expf(mo - M);
        se = se * w0 + seo * w1;
        st = st * w0 + sto * w1;
        mx = M;
    }
    if (lane < 16) {
        int l = cbase + l15;
        if (l < LDIM) {
            size_t o = (((size_t)b * NT + tile) * LDIM + l) * 3;
            part[o] = mx; part[o + 1] = se; part[o + 2] = st;
        }
    }
}

// ---- Merge NT tile partials -> logits ----
__global__ void final_kernel(const float* __restrict__ part, const float* __restrict__ final_b,
                             float* __restrict__ out)
{
    int b = blockIdx.x, l = threadIdx.x;
    if (l >= LDIM) return;
    float mx = -1e30f, se = 0.f, st = 0.f;
    for (int c = 0; c < NT; ++c) {
        size_t o = (((size_t)b * NT + c) * LDIM + l) * 3;
        float mo = part[o], seo = part[o + 1], sto = part[o + 2];
        float M  = fmaxf(mx, mo);
        float w0 = __expf(mx - M), w1 = __expf(mo - M);
        se = se * w0 + seo * w1;
        st = st * w0 + sto * w1;
        mx = M;
    }
    out[b * LDIM + l] = st / se + final_b[l];
}

extern "C" void kernel_launch(void* const* d_in, const int* in_sizes, int n_in,
                              void* d_out, int out_size, void* d_ws, size_t ws_size,
                              hipStream_t stream)
{
    const int*   ids     = (const int*)d_in[0];
    const float* emb     = (const float*)d_in[1];
    const float* conv_w  = (const float*)d_in[2];
    const float* conv_b  = (const float*)d_in[3];
    const float* U_w     = (const float*)d_in[4];
    const float* final_w = (const float*)d_in[5];
    const float* final_b = (const float*)d_in[6];

    char* ws = (char*)d_ws;
    size_t offE  = 0;
    size_t szE   = (size_t)30522 * 256 * 2;          // 15,627,264 B
    size_t offWb = offE + szE;
    size_t szWb  = 256 * 1024 * 2;                   // 524,288 B
    size_t offW2 = offWb + szWb;
    size_t szW2  = 32768 * 2;                        // 65,536 B
    size_t offZ  = offW2 + szW2;
    size_t szZ   = 512;
    size_t offP  = offZ + szZ;                       // 32*43*50*3 fp32 = 825,600 B

    unsigned short* embb = (unsigned short*)(ws + offE);
    unsigned short* Wb   = (unsigned short*)(ws + offWb);
    unsigned short* W2k  = (unsigned short*)(ws + offW2);
    uint32_t*       zp   = (uint32_t*)(ws + offZ);
    float*          prt  = (float*)(ws + offP);

    prep_misc<<<1024, 256, 0, stream>>>(conv_w, U_w, final_w, Wb, W2k, zp);
    prep_embb<<<3816, 256, 0, stream>>>(emb, embb);
    fused_kernel<<<dim3(NT, BDIM), 256, 0, stream>>>(ids, embb, Wb, conv_b, W2k, zp, prt);
    final_kernel<<<BDIM, 64, 0, stream>>>(prt, final_b, (float*)d_out);
}